// Round 8
// baseline (103.990 us; speedup 1.0000x reference)
//
#include <hip/hip_runtime.h>

#define BATCH 2
#define H 512
#define W 512
#define CS 21
#define CI 3
#define P 128                   // pixels per block (x)
#define R 8                     // output rows per block (vertical run)
#define TPB 256
#define GROWS (R + 2)           // 10 tap rows
#define NSETS (R * P)           // 1024 weight sets

typedef float f32x4 __attribute__((ext_vector_type(4)));

__device__ __forceinline__ void fma4(float4& a, const float4 v, const float w) {
    a.x = fmaf(v.x, w, a.x);
    a.y = fmaf(v.y, w, a.y);
    a.z = fmaf(v.z, w, a.z);
    a.w = fmaf(v.w, w, a.w);
}

// out is never re-read: nt store avoids L2 write-allocate evicting src halo.
__device__ __forceinline__ void nt_store4(float* p, const float4 v) {
    __builtin_nontemporal_store(*(const f32x4*)&v, (f32x4*)p);
}

// Load the 3 x-taps of one src row into a float4[3].
#define LOAD3(dst, rr, om, oc, op)                              \
    (dst)[0] = *(const float4*)(srow[rr] + (om));               \
    (dst)[1] = *(const float4*)(srow[rr] + (oc));               \
    (dst)[2] = *(const float4*)(srow[rr] + (op));

// Row selector: rows 0..5 live in va[6][3], rows 6..9 in vb[4][3].
#define VA_I(r) ((r) < 6 ? (r) : 5)
#define VB_I(r) ((r) < 6 ? 0 : (r) - 6)
#define VR(va, vb, r, k) ((r) < 6 ? (va)[VA_I(r)][(k)] : (vb)[VB_I(r)][(k)])

// 8-row vertical run: same fma ordering as champion (bit-identical output).
#define COMPUTE8(va, vb, px, oc)                                             \
    {                                                                        \
        _Pragma("unroll")                                                    \
        for (int j = 0; j < R; ++j) {                                        \
            const float* wd = &s_w[(((j << 7) + (px))) * 12];                \
            float4 wA = *(const float4*)(wd + 0);                            \
            float4 wB = *(const float4*)(wd + 4);                            \
            float  w8 = wd[8];                                               \
            float4 acc = {0.f, 0.f, 0.f, 0.f};                               \
            fma4(acc, VR(va, vb, j + 0, 0), wA.x);                           \
            fma4(acc, VR(va, vb, j + 0, 1), wA.y);                           \
            fma4(acc, VR(va, vb, j + 0, 2), wA.z);                           \
            fma4(acc, VR(va, vb, j + 1, 0), wA.w);                           \
            fma4(acc, VR(va, vb, j + 1, 1), wB.x);                           \
            fma4(acc, VR(va, vb, j + 1, 2), wB.y);                           \
            fma4(acc, VR(va, vb, j + 2, 0), wB.z);                           \
            fma4(acc, VR(va, vb, j + 2, 1), wB.w);                           \
            fma4(acc, VR(va, vb, j + 2, 2), w8);                             \
            nt_store4(ob + (size_t)j * rs + (oc), acc);                      \
        }                                                                    \
    }

// Champion (R=8/P=128/TPB=256, 100.07) with the guide-STAGING PHASE DELETED:
// weight phase reads im directly from global (im is 12.6MB, L2/L3-resident;
// FETCH counters show reads are cache-absorbed). Removes the global_load_lds
// loop, its vmcnt(0) drain, and barrier 1 -- the serial head that precedes
// every output store. ~92 extra VMEM wave-instrs/wave is the price; L1 dedups
// the 9x spatial overlap. Same guide floats, same reflect indexing, same
// k-order -> bit-identical output. One barrier remains (s_w write -> read).
__global__ __launch_bounds__(TPB, 2) void jbu_kernel(
    const float* __restrict__ src, const float* __restrict__ im,
    float* __restrict__ out)
{
    __shared__ __align__(16) float s_w[NSETS * 12];   // 49,152 B weights only

    const int t = threadIdx.x;

    // XCD swizzle: XCD (f&7) owns a contiguous 64-output-row band.
    const int f      = blockIdx.x;        // 0..511
    const int xcd    = f & 7;
    const int g      = f >> 3;            // 0..63
    const int rowgrp = (xcd << 3) | (g & 7);    // 0..63
    const int rem    = g >> 3;            // 0..7
    const int x0     = (rem & 3) << 7;    // segment * 128
    const int b      = rem >> 2;
    const int y0     = rowgrp << 3;       // output rows y0..y0+7

    const size_t rs = (size_t)W * CS;
    const float* sb  = src + (size_t)b * H * rs;
    const float* imb = im  + (size_t)b * (size_t)(H * W * CI);
    const float* srow[GROWS];             // wave-uniform -> SGPRs
    const float* grow[GROWS];             // guide row pointers (wave-uniform)
    #pragma unroll
    for (int rr = 0; rr < GROWS; ++rr) {
        int v = y0 - 1 + rr;
        int tyr = (v < 0) ? 1 : ((v >= H) ? 2 * H - 2 - v : v);
        srow[rr] = sb  + (size_t)tyr * rs;
        grow[rr] = imb + (size_t)tyr * (W * CI);
    }
    #pragma unroll
    for (int rr = 0; rr < GROWS; ++rr) srow[rr] += (size_t)x0 * CS;

    // ---- it=0 addressing + full 6-row prefetch (rows 0..5) ----
    const int px0   = t / 6;              // 0..42
    const int q0    = t - px0 * 6;
    const int coff0 = (q0 == 5) ? 17 : (q0 << 2);
    const int x_    = x0 + px0;
    const int xm_   = (x_ == 0)     ? 1     : x_ - 1;
    const int xp_   = (x_ == W - 1) ? W - 2 : x_ + 1;
    const int om0   = (xm_ - x0) * CS + coff0;   // may be negative: valid in-row
    const int oc0   = px0 * CS + coff0;
    const int op0   = (xp_ - x0) * CS + coff0;

    float4 va0[6][3];
    #pragma unroll
    for (int rr = 0; rr < 6; ++rr) { LOAD3(va0[rr], rr, om0, oc0, op0) }

    // ---- weight phase: 4 sets/thread, guide DIRECT from global ----
    // Set idx = ii*256+t  <=>  r = ii*2 + (t>>7) (wave-uniform), px = t&127.
    // Guide cols for px: reflected x0+px-1 .. x0+px+1 (same values the old
    // staging would have stored).
    {
        const int wpx = t & (P - 1);
        const int xg  = x0 + wpx;
        const int gxm = (xg == 0)     ? 1     : xg - 1;
        const int gxp = (xg == W - 1) ? W - 2 : xg + 1;
        const int cm  = gxm * CI;
        const int cc  = xg  * CI;
        const int cp  = gxp * CI;

        const float w1k[9] = {0.36787944f, 0.60653066f, 0.36787944f,
                              0.60653066f, 1.0f,        0.60653066f,
                              0.36787944f, 0.60653066f, 0.36787944f};
        #pragma unroll
        for (int ii = 0; ii < 4; ++ii) {
            const int r = ii * 2 + (t >> 7);       // wave-uniform
            const float* g0 = grow[r + 0];
            const float* g1 = grow[r + 1];
            const float* g2 = grow[r + 2];
            const float c0 = g1[cc + 0], c1 = g1[cc + 1], c2 = g1[cc + 2];
            float wv[9];
            float den = 0.f;
            #pragma unroll
            for (int k = 0; k < 9; ++k) {
                const int dy = k / 3, dx = k % 3;
                const float* gr = (dy == 0) ? g0 : ((dy == 1) ? g1 : g2);
                const int    cb = (dx == 0) ? cm : ((dx == 1) ? cc : cp);
                const float d0 = gr[cb + 0] - c0;
                const float d1 = gr[cb + 1] - c1;
                const float d2 = gr[cb + 2] - c2;
                const float w = __expf(-8.0f * (d0 * d0 + d1 * d1 + d2 * d2)) * w1k[k];
                wv[k] = w;
                den += w;
            }
            const float inv = 1.0f / den;
            float* wd = &s_w[(ii * TPB + t) * 12];
            *(float4*)(wd + 0) = make_float4(wv[0] * inv, wv[1] * inv, wv[2] * inv, wv[3] * inv);
            *(float4*)(wd + 4) = make_float4(wv[4] * inv, wv[5] * inv, wv[6] * inv, wv[7] * inv);
            wd[8] = wv[8] * inv;
        }
    }

    // ---- it=1 addressing + rows 0..3 prefetch: in flight across the barrier ----
    const int item1 = TPB + t;
    const int px1   = item1 / 6;          // 42..85
    const int q1    = item1 - px1 * 6;
    const int coff1 = (q1 == 5) ? 17 : (q1 << 2);
    const int x1    = x0 + px1;
    const int xm1   = (x1 == 0)     ? 1     : x1 - 1;
    const int xp1   = (x1 == W - 1) ? W - 2 : x1 + 1;
    const int om1   = (xm1 - x0) * CS + coff1;
    const int oc1   = px1 * CS + coff1;
    const int op1   = (xp1 - x0) * CS + coff1;

    float4 va1[6][3];
    #pragma unroll
    for (int rr = 0; rr < 4; ++rr) { LOAD3(va1[rr], rr, om1, oc1, op1) }

    __syncthreads();   // the ONLY barrier: s_w writes -> phase-2 reads

    // ---- phase 2: 8-row vertical runs, taps from global, weights from LDS ----
    float* ob = out + ((size_t)(b * H + y0)) * rs + (size_t)x0 * CS;

    // it = 0: va0 ready; fetch rows 6..9 (hidden under early-j fmas)
    {
        float4 vb0[4][3];
        #pragma unroll
        for (int rr = 0; rr < 4; ++rr) { LOAD3(vb0[rr], rr + 6, om0, oc0, op0) }
        COMPUTE8(va0, vb0, px0, oc0)
    }

    // it = 1: rows 0..3 prefetched; fetch rows 4..9
    {
        LOAD3(va1[4], 4, om1, oc1, op1)
        LOAD3(va1[5], 5, om1, oc1, op1)
        float4 vb1[4][3];
        #pragma unroll
        for (int rr = 0; rr < 4; ++rr) { LOAD3(vb1[rr], rr + 6, om1, oc1, op1) }
        COMPUTE8(va1, vb1, px1, oc1)
    }

    // it = 2: full load
    {
        const int item2 = 2 * TPB + t;
        const int px2   = item2 / 6;      // 85..127
        const int q2    = item2 - px2 * 6;
        const int coff2 = (q2 == 5) ? 17 : (q2 << 2);
        const int x2    = x0 + px2;
        const int xm2   = (x2 == 0)     ? 1     : x2 - 1;
        const int xp2   = (x2 == W - 1) ? W - 2 : x2 + 1;
        const int om2   = (xm2 - x0) * CS + coff2;
        const int oc2   = px2 * CS + coff2;
        const int op2   = (xp2 - x0) * CS + coff2;

        float4 va2[6][3];
        #pragma unroll
        for (int rr = 0; rr < 6; ++rr) { LOAD3(va2[rr], rr, om2, oc2, op2) }
        float4 vb2[4][3];
        #pragma unroll
        for (int rr = 0; rr < 4; ++rr) { LOAD3(vb2[rr], rr + 6, om2, oc2, op2) }
        COMPUTE8(va2, vb2, px2, oc2)
    }
}

extern "C" void kernel_launch(void* const* d_in, const int* in_sizes, int n_in,
                              void* d_out, int out_size, void* d_ws, size_t ws_size,
                              hipStream_t stream) {
    const float* src = (const float*)d_in[0];
    const float* im  = (const float*)d_in[1];
    float* out = (float*)d_out;
    dim3 grid((W / P) * (H / R) * BATCH, 1, 1);   // 512 blocks = 2/CU
    jbu_kernel<<<grid, TPB, 0, stream>>>(src, im, out);
}

// Round 10
// 102.695 us; speedup vs baseline: 1.0126x; 1.0126x over previous
//
#include <hip/hip_runtime.h>

#define BATCH 2
#define H 512
#define W 512
#define CS 21
#define CI 3
#define P 128                   // pixels per block (x)
#define R 8                     // output rows per block (vertical run)
#define TPB 256
#define GROWS (R + 2)           // 10 tap rows
#define GSL (P + 2)             // 130 guide slots incl. halo
#define GSZ (GROWS * GSL * CI)  // 3900 guide floats

typedef float f32x4 __attribute__((ext_vector_type(4)));

__device__ __forceinline__ void fma4(float4& a, const float4 v, const float w) {
    a.x = fmaf(v.x, w, a.x);
    a.y = fmaf(v.y, w, a.y);
    a.z = fmaf(v.z, w, a.z);
    a.w = fmaf(v.w, w, a.w);
}

// out is never re-read: nt store avoids L2 write-allocate evicting src halo.
__device__ __forceinline__ void nt_store4(float* p, const float4 v) {
    __builtin_nontemporal_store(*(const f32x4*)&v, (f32x4*)p);
}

// Load the 3 x-taps of one src row into a float4[3].
#define LOAD3(dst, rr, om, oc, op)                              \
    (dst)[0] = *(const float4*)(srow[rr] + (om));               \
    (dst)[1] = *(const float4*)(srow[rr] + (oc));               \
    (dst)[2] = *(const float4*)(srow[rr] + (op));

// Row selector: rows 0..5 live in va[6][3], rows 6..9 in vb[4][3].
// All indices are compile-time after unroll (rule #20: no scratch).
#define VA_I(r) ((r) < 6 ? (r) : 5)
#define VB_I(r) ((r) < 6 ? 0 : (r) - 6)
#define VR(va, vb, r, k) ((r) < 6 ? (va)[VA_I(r)][(k)] : (vb)[VB_I(r)][(k)])

// 8-row vertical run: same fma ordering as the R=4 kernel (bit-identical).
#define COMPUTE8(va, vb, px, oc)                                             \
    {                                                                        \
        _Pragma("unroll")                                                    \
        for (int j = 0; j < R; ++j) {                                        \
            const float* wd = &s_w[((j << 7) + (px)) * 12];                  \
            float4 wA = *(const float4*)(wd + 0);                            \
            float4 wB = *(const float4*)(wd + 4);                            \
            float  w8 = wd[8];                                               \
            float4 acc = {0.f, 0.f, 0.f, 0.f};                               \
            fma4(acc, VR(va, vb, j + 0, 0), wA.x);                           \
            fma4(acc, VR(va, vb, j + 0, 1), wA.y);                           \
            fma4(acc, VR(va, vb, j + 0, 2), wA.z);                           \
            fma4(acc, VR(va, vb, j + 1, 0), wA.w);                           \
            fma4(acc, VR(va, vb, j + 1, 1), wB.x);                           \
            fma4(acc, VR(va, vb, j + 1, 2), wB.y);                           \
            fma4(acc, VR(va, vb, j + 2, 0), wB.z);                           \
            fma4(acc, VR(va, vb, j + 2, 1), wB.w);                           \
            fma4(acc, VR(va, vb, j + 2, 2), w8);                             \
            nt_store4(ob + (size_t)j * rs + (oc), acc);                      \
        }                                                                    \
    }

// CHAMPION (benched 100.07 us): R=8 (10 tap rows / 8 output rows = 1.25x
// vertical overfetch), async guide staging, it0 6-row + it1 4-row prefetch
// overlapping the staged head, LDS weight sharing (6 threads/set), nt stores,
// XCD-aware swizzle. Eight structural variants (R3-R8: occupancy, LDS-union,
// barrier/staging removal, rolling barrier-free) all regressed vs this.
__global__ __launch_bounds__(TPB, 2) void jbu_kernel(
    const float* __restrict__ src, const float* __restrict__ im,
    float* __restrict__ out)
{
    __shared__ float s_g[GSZ];                       // 15,600 B guide tile
    __shared__ __align__(16) float s_w[R * P * 12];  // 49,152 B weights

    const int t = threadIdx.x;

    // XCD swizzle: XCD (f&7) owns a contiguous 64-output-row band.
    const int f      = blockIdx.x;        // 0..511
    const int xcd    = f & 7;
    const int g      = f >> 3;            // 0..63
    const int rowgrp = (xcd << 3) | (g & 7);    // 0..63
    const int rem    = g >> 3;            // 0..7
    const int x0     = (rem & 3) << 7;    // segment * 128
    const int b      = rem >> 2;
    const int y0     = rowgrp << 3;       // output rows y0..y0+7

    const size_t rs = (size_t)W * CS;
    const float* sb = src + (size_t)b * H * rs;
    const float* srow[GROWS];
    #pragma unroll
    for (int rr = 0; rr < GROWS; ++rr) {
        int v = y0 - 1 + rr;
        int tyr = (v < 0) ? 1 : ((v >= H) ? 2 * H - 2 - v : v);
        srow[rr] = sb + (size_t)tyr * rs + (size_t)x0 * CS;
    }

    // ---- it=0 addressing + full 6-row prefetch (rows 0..5) ----
    const int px0   = t / 6;              // 0..42
    const int q0    = t - px0 * 6;
    const int coff0 = (q0 == 5) ? 17 : (q0 << 2);
    const int x_    = x0 + px0;
    const int xm_   = (x_ == 0)     ? 1     : x_ - 1;
    const int xp_   = (x_ == W - 1) ? W - 2 : x_ + 1;
    const int om0   = (xm_ - x0) * CS + coff0;   // may be negative: valid in-row
    const int oc0   = px0 * CS + coff0;
    const int op0   = (xp_ - x0) * CS + coff0;

    float4 va0[6][3];
    #pragma unroll
    for (int rr = 0; rr < 6; ++rr) { LOAD3(va0[rr], rr, om0, oc0, op0) }

    // ---- stage guide tile: async global->LDS (linear dest = base + lane*4) ----
    const float* imb = im + (size_t)b * (H * W * CI);
    for (int i = t; i < GSZ; i += TPB) {
        int rr   = i / (GSL * CI);
        int remi = i - rr * (GSL * CI);
        int slot = remi / CI;
        int ch   = remi - slot * CI;
        int gx   = x0 + slot - 1;
        gx = (gx < 0) ? 1 : ((gx >= W) ? W - 2 : gx);
        int vv = y0 - 1 + rr;
        int tyr = (vv < 0) ? 1 : ((vv >= H) ? 2 * H - 2 - vv : vv);
        const float* gsrc = imb + ((size_t)tyr * W + gx) * CI + ch;
        __builtin_amdgcn_global_load_lds(
            (const __attribute__((address_space(1))) void*)gsrc,
            (__attribute__((address_space(3))) void*)(s_g + i), 4, 0, 0);
    }
    __syncthreads();

    // ---- it=1 addressing + rows 0..3 prefetch: streams during weight phase ----
    const int item1 = TPB + t;
    const int px1   = item1 / 6;          // 42..85
    const int q1    = item1 - px1 * 6;
    const int coff1 = (q1 == 5) ? 17 : (q1 << 2);
    const int x1    = x0 + px1;
    const int xm1   = (x1 == 0)     ? 1     : x1 - 1;
    const int xp1   = (x1 == W - 1) ? W - 2 : x1 + 1;
    const int om1   = (xm1 - x0) * CS + coff1;
    const int oc1   = px1 * CS + coff1;
    const int op1   = (xp1 - x0) * CS + coff1;

    float4 va1[6][3];
    #pragma unroll
    for (int rr = 0; rr < 4; ++rr) { LOAD3(va1[rr], rr, om1, oc1, op1) }

    // ---- weights: R*P = 1024 sets, 4 per thread, normalized ----
    {
        const float w1k[9] = {0.36787944f, 0.60653066f, 0.36787944f,
                              0.60653066f, 1.0f,        0.60653066f,
                              0.36787944f, 0.60653066f, 0.36787944f};
        #pragma unroll
        for (int ii = 0; ii < (R * P) / TPB; ++ii) {
            int idx = ii * TPB + t;       // 0..1023
            int r   = idx >> 7;           // 0..7   (idx / P)
            int px  = idx & (P - 1);
            int cb  = ((r + 1) * GSL + px + 1) * CI;
            float c0 = s_g[cb + 0], c1 = s_g[cb + 1], c2 = s_g[cb + 2];
            float wv[9];
            float den = 0.f;
            #pragma unroll
            for (int k = 0; k < 9; ++k) {
                int dy = k / 3, dx = k % 3;
                int ib = ((r + dy) * GSL + px + dx) * CI;
                float d0 = s_g[ib + 0] - c0;
                float d1 = s_g[ib + 1] - c1;
                float d2 = s_g[ib + 2] - c2;
                float w = __expf(-8.0f * (d0 * d0 + d1 * d1 + d2 * d2)) * w1k[k];
                wv[k] = w;
                den += w;
            }
            float inv = 1.0f / den;
            float* wd = &s_w[idx * 12];
            *(float4*)(wd + 0) = make_float4(wv[0] * inv, wv[1] * inv, wv[2] * inv, wv[3] * inv);
            *(float4*)(wd + 4) = make_float4(wv[4] * inv, wv[5] * inv, wv[6] * inv, wv[7] * inv);
            wd[8] = wv[8] * inv;
        }
    }
    __syncthreads();

    // ---- phase 2: 8-row vertical runs, taps from global, weights from LDS ----
    float* ob = out + ((size_t)(b * H + y0)) * rs + (size_t)x0 * CS;

    // it = 0: va0 ready; fetch rows 6..9 (hidden under early-j fmas)
    {
        float4 vb0[4][3];
        #pragma unroll
        for (int rr = 0; rr < 4; ++rr) { LOAD3(vb0[rr], rr + 6, om0, oc0, op0) }
        COMPUTE8(va0, vb0, px0, oc0)
    }

    // it = 1: rows 0..3 prefetched; fetch rows 4..9
    {
        LOAD3(va1[4], 4, om1, oc1, op1)
        LOAD3(va1[5], 5, om1, oc1, op1)
        float4 vb1[4][3];
        #pragma unroll
        for (int rr = 0; rr < 4; ++rr) { LOAD3(vb1[rr], rr + 6, om1, oc1, op1) }
        COMPUTE8(va1, vb1, px1, oc1)
    }

    // it = 2: full load
    {
        const int item2 = 2 * TPB + t;
        const int px2   = item2 / 6;      // 85..127
        const int q2    = item2 - px2 * 6;
        const int coff2 = (q2 == 5) ? 17 : (q2 << 2);
        const int x2    = x0 + px2;
        const int xm2   = (x2 == 0)     ? 1     : x2 - 1;
        const int xp2   = (x2 == W - 1) ? W - 2 : x2 + 1;
        const int om2   = (xm2 - x0) * CS + coff2;
        const int oc2   = px2 * CS + coff2;
        const int op2   = (xp2 - x0) * CS + coff2;

        float4 va2[6][3];
        #pragma unroll
        for (int rr = 0; rr < 6; ++rr) { LOAD3(va2[rr], rr, om2, oc2, op2) }
        float4 vb2[4][3];
        #pragma unroll
        for (int rr = 0; rr < 4; ++rr) { LOAD3(vb2[rr], rr + 6, om2, oc2, op2) }
        COMPUTE8(va2, vb2, px2, oc2)
    }
}

extern "C" void kernel_launch(void* const* d_in, const int* in_sizes, int n_in,
                              void* d_out, int out_size, void* d_ws, size_t ws_size,
                              hipStream_t stream) {
    const float* src = (const float*)d_in[0];
    const float* im  = (const float*)d_in[1];
    float* out = (float*)d_out;
    dim3 grid((W / P) * (H / R) * BATCH, 1, 1);   // 512 blocks = 2/CU
    jbu_kernel<<<grid, TPB, 0, stream>>>(src, im, out);
}